// Round 1
// baseline (208.428 us; speedup 1.0000x reference)
//
#include <hip/hip_runtime.h>

#define RELN 8
#define DIMN 256
#define BN_  8
#define SN   512
#define TN   512

typedef __attribute__((ext_vector_type(8))) short bf16x8;   // 8 bf16 payloads
typedef __attribute__((ext_vector_type(4))) short bf16x4;
typedef __attribute__((ext_vector_type(4))) float f32x4;

__device__ __forceinline__ unsigned short f2bf(float f) {
    union { float f; unsigned u; } x; x.f = f;
    return (unsigned short)((x.u + 0x7FFFu + ((x.u >> 16) & 1u)) >> 16);  // RNE
}

// ---------------------------------------------------------------------------
// Generic bf16 MFMA GEMM, B^T layout (A: MxK row-major, B: NxK row-major).
// 128x128 tile, BK=64, 4 waves each computing a 64x64 quadrant (4x4 frags of
// 16x16x32). LDS rows padded to 72 shorts (144B) to keep 16B alignment and
// spread frag reads across bank quads (2-way max -> free per m136).
// MODE 1: scores = src_bf @ WscoreT[r]          (z=r,      bf16 out)
// MODE 2: st     = scores[r,b] @ tar_bf[b]^T    (z=r*8+b,  f32 out)
// MODE 3: relT   = tar_bf @ WembT[r], TRANSPOSED store (r,b,e,t) (z=r, bf16)
// MODE 4: out   += w[r,b] @ relT[r,b]^T * 1/sqrt(8)  (z=r, f32 atomicAdd)
// ---------------------------------------------------------------------------
#define TBM 128
#define TBN 128
#define TBK 64
#define LDT 72

template<int MODE>
__global__ __launch_bounds__(256, 2)
void gemm_bt(const unsigned short* __restrict__ A,
             const unsigned short* __restrict__ B,
             void* __restrict__ C, int K, int lda, int ldb)
{
    __shared__ unsigned short As[TBM * LDT];
    __shared__ unsigned short Bs[TBN * LDT];
    const int tid  = threadIdx.x;
    const int lane = tid & 63;
    const int wv   = tid >> 6;
    const int wr   = (wv >> 1) * 64;
    const int wc   = (wv & 1) * 64;
    const int m0   = blockIdx.x * TBM;
    const int n0   = blockIdx.y * TBN;
    const int z    = blockIdx.z;

    const unsigned short* Ab = A;
    const unsigned short* Bb = B;
    if (MODE == 1)      { Bb += (size_t)z * DIMN * DIMN; }
    else if (MODE == 2) { Ab += (size_t)z * SN * DIMN; Bb += (size_t)(z & 7) * TN * DIMN; }
    else if (MODE == 3) { Bb += (size_t)z * DIMN * DIMN; }
    else                { Ab += (size_t)z * (BN_*SN) * TN;
                          Bb += ((size_t)z * (BN_*DIMN) + (size_t)(m0 >> 9) * DIMN) * TN; }

    f32x4 acc[4][4] = {};

    for (int kt = 0; kt < K; kt += TBK) {
        __syncthreads();
        #pragma unroll
        for (int it = 0; it < 4; ++it) {
            int idx = it * 256 + tid;
            int row = idx >> 3;
            int cg  = (idx & 7) * 8;
            *(bf16x8*)&As[row*LDT + cg] = *(const bf16x8*)&Ab[(size_t)(m0 + row)*lda + kt + cg];
            *(bf16x8*)&Bs[row*LDT + cg] = *(const bf16x8*)&Bb[(size_t)(n0 + row)*ldb + kt + cg];
        }
        __syncthreads();
        #pragma unroll
        for (int kk = 0; kk < 2; ++kk) {
            const int ko = kk*32 + (lane >> 4) * 8;
            bf16x8 af[4], bfv[4];
            #pragma unroll
            for (int i = 0; i < 4; ++i)
                af[i] = *(const bf16x8*)&As[(wr + i*16 + (lane & 15))*LDT + ko];
            #pragma unroll
            for (int j = 0; j < 4; ++j)
                bfv[j] = *(const bf16x8*)&Bs[(wc + j*16 + (lane & 15))*LDT + ko];
            #pragma unroll
            for (int i = 0; i < 4; ++i) {
                #pragma unroll
                for (int j = 0; j < 4; ++j)
                    acc[i][j] = __builtin_amdgcn_mfma_f32_16x16x32_bf16(af[i], bfv[j], acc[i][j], 0, 0, 0);
            }
        }
    }

    // C/D frag mapping (m89-verified): col = lane&15, row = (lane>>4)*4 + reg
    const int r0 = (lane >> 4) * 4;
    const int cl = lane & 15;
    if (MODE == 2) {
        float* Cp = (float*)C + (size_t)z * SN * TN;
        #pragma unroll
        for (int i = 0; i < 4; ++i) {
            int row = m0 + wr + i*16 + r0;
            #pragma unroll
            for (int j = 0; j < 4; ++j) {
                int col = n0 + wc + j*16 + cl;
                #pragma unroll
                for (int q = 0; q < 4; ++q)
                    Cp[(size_t)(row + q)*TN + col] = acc[i][j][q];
            }
        }
    } else if (MODE == 1) {
        unsigned short* Cp = (unsigned short*)C + (size_t)z * (BN_*SN) * DIMN;
        #pragma unroll
        for (int i = 0; i < 4; ++i) {
            int row = m0 + wr + i*16 + r0;
            #pragma unroll
            for (int j = 0; j < 4; ++j) {
                int col = n0 + wc + j*16 + cl;
                #pragma unroll
                for (int q = 0; q < 4; ++q)
                    Cp[(size_t)(row + q)*DIMN + col] = f2bf(acc[i][j][q]);
            }
        }
    } else if (MODE == 3) {
        // relT[(z*8 + b)*256 + e][t], m = b*512 + t; 4 regs = 4 consecutive t
        unsigned short* Cp = (unsigned short*)C;
        #pragma unroll
        for (int i = 0; i < 4; ++i) {
            int mrow = m0 + wr + i*16 + r0;
            int b = mrow >> 9, t = mrow & 511;
            #pragma unroll
            for (int j = 0; j < 4; ++j) {
                int e = n0 + wc + j*16 + cl;
                bf16x4 v;
                #pragma unroll
                for (int q = 0; q < 4; ++q) v[q] = (short)f2bf(acc[i][j][q]);
                *(bf16x4*)&Cp[((size_t)(z*BN_ + b)*DIMN + e)*TN + t] = v;
            }
        }
    } else {
        float* Cp = (float*)C;
        #pragma unroll
        for (int i = 0; i < 4; ++i) {
            int row = m0 + wr + i*16 + r0;
            #pragma unroll
            for (int j = 0; j < 4; ++j) {
                int col = n0 + wc + j*16 + cl;
                #pragma unroll
                for (int q = 0; q < 4; ++q)
                    atomicAdd(&Cp[(size_t)(row + q)*DIMN + col],
                              acc[i][j][q] * 0.35355339059327373f);
            }
        }
    }
}

// f32 -> bf16, 4 elems/thread
__global__ void cvt_bf16_kernel(const float* __restrict__ in,
                                unsigned short* __restrict__ out, int n4)
{
    int i = (blockIdx.x * 256 + threadIdx.x) * 4;
    if (i < n4) {
        float4 v = *(const float4*)(in + i);
        bf16x4 o;
        o[0] = (short)f2bf(v.x); o[1] = (short)f2bf(v.y);
        o[2] = (short)f2bf(v.z); o[3] = (short)f2bf(v.w);
        *(bf16x4*)(out + i) = o;
    }
}

// W (REL,DIM,DIM)[r][d][e] f32 -> WT[r][e][d] bf16, 32x32 LDS tile transpose
__global__ void wtrans_kernel(const float* __restrict__ w,
                              unsigned short* __restrict__ wt)
{
    __shared__ float tile[32][33];
    int r = blockIdx.z;
    int e0 = blockIdx.x * 32, d0 = blockIdx.y * 32;
    int tx = threadIdx.x & 31, ty = threadIdx.x >> 5;  // 256 thr: ty 0..7
    #pragma unroll
    for (int k = 0; k < 32; k += 8)
        tile[ty + k][tx] = w[((size_t)r*DIMN + d0 + ty + k)*DIMN + e0 + tx];
    __syncthreads();
    #pragma unroll
    for (int k = 0; k < 32; k += 8)
        wt[((size_t)r*DIMN + e0 + ty + k)*DIMN + d0 + tx] = f2bf(tile[tx][ty + k]);
}

// scores_none[r][e] = sum_d src_none[d] * Wscore[r][d][e]   (f32, tiny)
__global__ void scores_none_kernel(const float* __restrict__ w,
                                   const float* __restrict__ none,
                                   float* __restrict__ out)
{
    int r = blockIdx.x, e = threadIdx.x;
    float acc = 0.f;
    for (int d = 0; d < DIMN; ++d)
        acc += none[d] * w[((size_t)r*DIMN + d)*DIMN + e];
    out[r*DIMN + e] = acc;
}

// st_none[r,b,t] = sum_e scores_none[r][e] * tar_emb[b][t][e]   (f32)
__global__ void st_none_kernel(const float* __restrict__ sc_none,
                               const float* __restrict__ tar_emb,
                               float* __restrict__ stn)
{
    __shared__ float sn[DIMN];
    int rb = blockIdx.x, r = rb >> 3, b = rb & 7;
    sn[threadIdx.x] = sc_none[r*DIMN + threadIdx.x];
    __syncthreads();
    for (int t = threadIdx.x; t < TN; t += 256) {
        const float4* row = (const float4*)(tar_emb + ((size_t)b*TN + t)*DIMN);
        float acc = 0.f;
        for (int e4 = 0; e4 < DIMN/4; ++e4) {
            float4 v = row[e4];
            acc += v.x*sn[e4*4] + v.y*sn[e4*4+1] + v.z*sn[e4*4+2] + v.w*sn[e4*4+3];
        }
        stn[(size_t)rb*TN + t] = acc;
    }
}

// Column softmax over s (513 rows: 512 + none), write w bf16 for s<512.
// Block: 256 thr = 4 waves; 64 columns/block; wave w handles s in [w*128,(w+1)*128)
// (wave 3 also folds in the none row). Online max+sum, merged via LDS.
__global__ void softmax_kernel(const float* __restrict__ st,
                               const float* __restrict__ st_none,
                               const float* __restrict__ src_mask,
                               const float* __restrict__ tar_mask,
                               unsigned short* __restrict__ wout)
{
    __shared__ float pm[4][64], pl[4][64], fm[64], fl[64], smask[SN];
    int rb = blockIdx.y, b = rb & 7;
    int lane = threadIdx.x & 63, wv = threadIdx.x >> 6;
    int t = blockIdx.x * 64 + lane;
    float tarm = tar_mask[b*TN + t];
    for (int i = threadIdx.x; i < SN; i += 256) smask[i] = src_mask[b*SN + i];
    __syncthreads();
    const float* col = st + (size_t)rb*(SN*TN) + t;
    float m = -1e30f, l = 0.f;
    for (int s = wv*128; s < wv*128 + 128; ++s) {
        float v = (col[(size_t)s*TN] + (1.f - smask[s]*tarm) * -1e10f) * 0.0625f;
        if (v > m) { l = l*__expf(m - v) + 1.f; m = v; } else l += __expf(v - m);
    }
    if (wv == 3) {  // none row: src_mask_ = 1
        float v = (st_none[(size_t)rb*TN + t] + (1.f - tarm) * -1e10f) * 0.0625f;
        if (v > m) { l = l*__expf(m - v) + 1.f; m = v; } else l += __expf(v - m);
    }
    pm[wv][lane] = m; pl[wv][lane] = l;
    __syncthreads();
    if (threadIdx.x < 64) {
        float M = pm[0][lane];
        #pragma unroll
        for (int k = 1; k < 4; ++k) M = fmaxf(M, pm[k][lane]);
        float L = 0.f;
        #pragma unroll
        for (int k = 0; k < 4; ++k) L += pl[k][lane] * __expf(pm[k][lane] - M);
        fm[lane] = M; fl[lane] = 1.f / L;
    }
    __syncthreads();
    float M = fm[lane], invL = fl[lane];
    unsigned short* wc = wout + (size_t)rb*(SN*TN) + t;
    for (int s = wv*128; s < wv*128 + 128; ++s) {
        float v = (col[(size_t)s*TN] + (1.f - smask[s]*tarm) * -1e10f) * 0.0625f;
        wc[(size_t)s*TN] = f2bf(__expf(v - M) * invL);
    }
}

extern "C" void kernel_launch(void* const* d_in, const int* in_sizes, int n_in,
                              void* d_out, int out_size, void* d_ws, size_t ws_size,
                              hipStream_t stream)
{
    const float* src_emb  = (const float*)d_in[0];
    const float* tar_emb  = (const float*)d_in[1];
    const float* src_mask = (const float*)d_in[2];
    const float* tar_mask = (const float*)d_in[3];
    const float* w_score  = (const float*)d_in[4];
    const float* w_emb    = (const float*)d_in[5];
    const float* src_none = (const float*)d_in[6];
    // tar_none_node (d_in[7]) provably never reaches the output (t=512 sliced off)

    size_t off = 0;
    auto alloc = [&](size_t bytes) {
        char* q = (char*)d_ws + off;
        off += (bytes + 255) & ~(size_t)255;
        return q;
    };
    unsigned short* src_bf  = (unsigned short*)alloc((size_t)BN_*SN*DIMN*2);      // 2 MB
    unsigned short* tar_bf  = (unsigned short*)alloc((size_t)BN_*TN*DIMN*2);      // 2 MB
    unsigned short* wscT    = (unsigned short*)alloc((size_t)RELN*DIMN*DIMN*2);   // 1 MB
    unsigned short* wembT   = (unsigned short*)alloc((size_t)RELN*DIMN*DIMN*2);   // 1 MB
    unsigned short* scores  = (unsigned short*)alloc((size_t)RELN*BN_*SN*DIMN*2); // 16 MB
    float*          st      = (float*)alloc((size_t)RELN*BN_*SN*TN*4);            // 64 MB
    unsigned short* wbuf    = (unsigned short*)alloc((size_t)RELN*BN_*SN*TN*2);   // 32 MB
    unsigned short* relT    = (unsigned short*)alloc((size_t)RELN*BN_*DIMN*TN*2); // 16 MB
    float*          sc_none = (float*)alloc((size_t)RELN*DIMN*4);
    float*          stn     = (float*)alloc((size_t)RELN*BN_*TN*4);
    if (off > ws_size) return;  // fails loudly (output stays zero)

    hipMemsetAsync(d_out, 0, (size_t)out_size * 4, stream);

    cvt_bf16_kernel<<<1024, 256, 0, stream>>>(src_emb, src_bf, BN_*SN*DIMN);
    cvt_bf16_kernel<<<1024, 256, 0, stream>>>(tar_emb, tar_bf, BN_*TN*DIMN);
    wtrans_kernel<<<dim3(8,8,8), 256, 0, stream>>>(w_score, wscT);
    wtrans_kernel<<<dim3(8,8,8), 256, 0, stream>>>(w_emb,  wembT);
    scores_none_kernel<<<RELN, 256, 0, stream>>>(w_score, src_none, sc_none);

    // GEMM1: scores (R, B*S, DIM) = src_bf (B*S, DIM) @ WscoreT[r]
    gemm_bt<1><<<dim3(32, 2, 8), 256, 0, stream>>>(src_bf, wscT, scores, DIMN, DIMN, DIMN);
    // st_none (R*B, T)
    st_none_kernel<<<RELN*BN_, 256, 0, stream>>>(sc_none, tar_emb, stn);
    // GEMM2: st (R*B, S, T) f32 = scores[r,b] @ tar_bf[b]^T
    gemm_bt<2><<<dim3(4, 4, 64), 256, 0, stream>>>(scores, tar_bf, st, DIMN, DIMN, DIMN);
    // softmax over s -> w bf16 (R,B,S,T)
    softmax_kernel<<<dim3(8, 64), 256, 0, stream>>>(st, stn, src_mask, tar_mask, wbuf);
    // GEMM3: relT (R,B,DIM,T) bf16 = (tar_bf @ WembT[r]) transposed-stored
    gemm_bt<3><<<dim3(32, 2, 8), 256, 0, stream>>>(tar_bf, wembT, relT, DIMN, DIMN, DIMN);
    // GEMM4: out (B*S, DIM) += w[r,b] @ relT[r,b]^T * 1/sqrt(8), atomic over r
    gemm_bt<4><<<dim3(32, 2, 8), 256, 0, stream>>>(wbuf, relT, d_out, TN, TN, TN);
}

// Round 4
// 115.623 us; speedup vs baseline: 1.8027x; 1.8027x over previous
//
#include <hip/hip_runtime.h>

#define RELN 8
#define DIMN 256
#define BN_  8
#define SN   512
#define TN   512

typedef __attribute__((ext_vector_type(8))) short bf16x8;   // 8 bf16 payloads
typedef __attribute__((ext_vector_type(4))) short bf16x4;
typedef __attribute__((ext_vector_type(4))) float f32x4;

__device__ __forceinline__ unsigned short f2bf(float f) {
    union { float f; unsigned u; } x; x.f = f;
    return (unsigned short)((x.u + 0x7FFFu + ((x.u >> 16) & 1u)) >> 16);  // RNE
}

// ---------------------------------------------------------------------------
// Generic bf16 MFMA GEMM, B^T layout (A: MxK row-major, B: NxK row-major).
// 128x128 tile, BK=64, 4 waves each computing a 64x64 quadrant (4x4 frags of
// 16x16x32).
// MODE 1: scores = src_bf @ WscoreT[r]                     (z=r,      bf16)
// MODE 2: w~ = exp(mask(scores[r,b] @ tar_bf[b]^T)/16)     (z=r*8+b,  bf16)
//         + column-sum atomicAdd into L[rb][t]  (softmax WITHOUT max-sub:
//         logits bounded ~|6| by construction, exp never overflows f32)
// MODE 3: relT = (tar_bf @ WembT[r]) / L[rb][t], transposed store (r,b,e,t)
// MODE 4: out += w~[r,b] @ relT[r,b]^T * 1/sqrt(8)         (z=r, f32 atomic)
// ---------------------------------------------------------------------------
#define TBM 128
#define TBN 128
#define TBK 64
#define LDT 72

template<int MODE>
__global__ __launch_bounds__(256, 2)
void gemm_bt(const unsigned short* __restrict__ A,
             const unsigned short* __restrict__ B,
             void* __restrict__ C, int K, int lda, int ldb,
             const float* __restrict__ msrc,
             const float* __restrict__ mtar,
             float* __restrict__ Lsum)
{
    __shared__ unsigned short As[TBM * LDT];
    __shared__ unsigned short Bs[TBN * LDT];
    const int tid  = threadIdx.x;
    const int lane = tid & 63;
    const int wv   = tid >> 6;
    const int wr   = (wv >> 1) * 64;
    const int wc   = (wv & 1) * 64;
    const int m0   = blockIdx.x * TBM;
    const int n0   = blockIdx.y * TBN;
    const int z    = blockIdx.z;

    const unsigned short* Ab = A;
    const unsigned short* Bb = B;
    if (MODE == 1)      { Bb += (size_t)z * DIMN * DIMN; }
    else if (MODE == 2) { Ab += (size_t)z * SN * DIMN; Bb += (size_t)(z & 7) * TN * DIMN; }
    else if (MODE == 3) { Bb += (size_t)z * DIMN * DIMN; }
    else                { Ab += (size_t)z * (BN_*SN) * TN;
                          Bb += ((size_t)z * (BN_*DIMN) + (size_t)(m0 >> 9) * DIMN) * TN; }

    f32x4 acc[4][4] = {};

    for (int kt = 0; kt < K; kt += TBK) {
        __syncthreads();
        #pragma unroll
        for (int it = 0; it < 4; ++it) {
            int idx = it * 256 + tid;
            int row = idx >> 3;
            int cg  = (idx & 7) * 8;
            *(bf16x8*)&As[row*LDT + cg] = *(const bf16x8*)&Ab[(size_t)(m0 + row)*lda + kt + cg];
            *(bf16x8*)&Bs[row*LDT + cg] = *(const bf16x8*)&Bb[(size_t)(n0 + row)*ldb + kt + cg];
        }
        __syncthreads();
        #pragma unroll
        for (int kk = 0; kk < 2; ++kk) {
            const int ko = kk*32 + (lane >> 4) * 8;
            bf16x8 af[4], bfv[4];
            #pragma unroll
            for (int i = 0; i < 4; ++i)
                af[i] = *(const bf16x8*)&As[(wr + i*16 + (lane & 15))*LDT + ko];
            #pragma unroll
            for (int j = 0; j < 4; ++j)
                bfv[j] = *(const bf16x8*)&Bs[(wc + j*16 + (lane & 15))*LDT + ko];
            #pragma unroll
            for (int i = 0; i < 4; ++i) {
                #pragma unroll
                for (int j = 0; j < 4; ++j)
                    acc[i][j] = __builtin_amdgcn_mfma_f32_16x16x32_bf16(af[i], bfv[j], acc[i][j], 0, 0, 0);
            }
        }
    }

    // C/D frag mapping (m89-verified): col = lane&15, row = (lane>>4)*4 + reg
    const int r0 = (lane >> 4) * 4;
    const int cl = lane & 15;
    if (MODE == 2) {
        unsigned short* Cp = (unsigned short*)C + (size_t)z * SN * TN;
        const int b = z & 7;
        float tm[4];
        #pragma unroll
        for (int j = 0; j < 4; ++j) tm[j] = mtar[b*TN + n0 + wc + j*16 + cl];
        float colsum[4] = {0.f, 0.f, 0.f, 0.f};
        #pragma unroll
        for (int i = 0; i < 4; ++i) {
            int rowb = m0 + wr + i*16 + r0;
            float sm[4];
            #pragma unroll
            for (int q = 0; q < 4; ++q) sm[q] = msrc[b*SN + rowb + q];
            #pragma unroll
            for (int j = 0; j < 4; ++j) {
                int col = n0 + wc + j*16 + cl;
                #pragma unroll
                for (int q = 0; q < 4; ++q) {
                    float v = (acc[i][j][q] + (1.f - sm[q]*tm[j]) * -1e10f) * 0.0625f;
                    float e = __expf(v);
                    Cp[(size_t)(rowb + q)*TN + col] = f2bf(e);
                    colsum[j] += e;
                }
            }
        }
        // reduce the 4 row-groups (lane>>4) holding the same column, then atomic
        #pragma unroll
        for (int j = 0; j < 4; ++j) {
            float v = colsum[j];
            v += __shfl_xor(v, 16, 64);
            v += __shfl_xor(v, 32, 64);
            if (lane < 16)
                atomicAdd(&Lsum[(size_t)z*TN + n0 + wc + j*16 + cl], v);
        }
    } else if (MODE == 1) {
        unsigned short* Cp = (unsigned short*)C + (size_t)z * (BN_*SN) * DIMN;
        #pragma unroll
        for (int i = 0; i < 4; ++i) {
            int row = m0 + wr + i*16 + r0;
            #pragma unroll
            for (int j = 0; j < 4; ++j) {
                int col = n0 + wc + j*16 + cl;
                #pragma unroll
                for (int q = 0; q < 4; ++q)
                    Cp[(size_t)(row + q)*DIMN + col] = f2bf(acc[i][j][q]);
            }
        }
    } else if (MODE == 3) {
        // relT[(z*8 + b)*256 + e][t], m = b*512 + t; 4 regs = 4 consecutive t
        // normalized by the softmax denominator L[rb][t]
        unsigned short* Cp = (unsigned short*)C;
        #pragma unroll
        for (int i = 0; i < 4; ++i) {
            int mrow = m0 + wr + i*16 + r0;
            int b = mrow >> 9, t = mrow & 511;
            float4 Lv = *(const float4*)&Lsum[((size_t)(z*BN_ + b))*TN + t];
            float inv0 = 1.f / Lv.x, inv1 = 1.f / Lv.y,
                  inv2 = 1.f / Lv.z, inv3 = 1.f / Lv.w;
            #pragma unroll
            for (int j = 0; j < 4; ++j) {
                int e = n0 + wc + j*16 + cl;
                bf16x4 v;
                v[0] = (short)f2bf(acc[i][j][0] * inv0);
                v[1] = (short)f2bf(acc[i][j][1] * inv1);
                v[2] = (short)f2bf(acc[i][j][2] * inv2);
                v[3] = (short)f2bf(acc[i][j][3] * inv3);
                *(bf16x4*)&Cp[((size_t)(z*BN_ + b)*DIMN + e)*TN + t] = v;
            }
        }
    } else {
        float* Cp = (float*)C;
        #pragma unroll
        for (int i = 0; i < 4; ++i) {
            int row = m0 + wr + i*16 + r0;
            #pragma unroll
            for (int j = 0; j < 4; ++j) {
                int col = n0 + wc + j*16 + cl;
                #pragma unroll
                for (int q = 0; q < 4; ++q)
                    atomicAdd(&Cp[(size_t)(row + q)*DIMN + col],
                              acc[i][j][q] * 0.35355339059327373f);
            }
        }
    }
}

// f32 -> bf16, 4 elems/thread
__global__ void cvt_bf16_kernel(const float* __restrict__ in,
                                unsigned short* __restrict__ out, int n4)
{
    int i = (blockIdx.x * 256 + threadIdx.x) * 4;
    if (i < n4) {
        float4 v = *(const float4*)(in + i);
        bf16x4 o;
        o[0] = (short)f2bf(v.x); o[1] = (short)f2bf(v.y);
        o[2] = (short)f2bf(v.z); o[3] = (short)f2bf(v.w);
        *(bf16x4*)(out + i) = o;
    }
}

// W (REL,DIM,DIM)[r][d][e] f32 -> WT[r][e][d] bf16, 32x32 LDS tile transpose
__global__ void wtrans_kernel(const float* __restrict__ w,
                              unsigned short* __restrict__ wt)
{
    __shared__ float tile[32][33];
    int r = blockIdx.z;
    int e0 = blockIdx.x * 32, d0 = blockIdx.y * 32;
    int tx = threadIdx.x & 31, ty = threadIdx.x >> 5;  // 256 thr: ty 0..7
    #pragma unroll
    for (int k = 0; k < 32; k += 8)
        tile[ty + k][tx] = w[((size_t)r*DIMN + d0 + ty + k)*DIMN + e0 + tx];
    __syncthreads();
    #pragma unroll
    for (int k = 0; k < 32; k += 8)
        wt[((size_t)r*DIMN + e0 + ty + k)*DIMN + d0 + tx] = f2bf(tile[tx][ty + k]);
}

// scores_none[r][e] = sum_d src_none[d] * Wscore[r][d][e]   (f32, tiny)
__global__ void scores_none_kernel(const float* __restrict__ w,
                                   const float* __restrict__ none,
                                   float* __restrict__ out)
{
    int r = blockIdx.x, e = threadIdx.x;
    float acc = 0.f;
    for (int d = 0; d < DIMN; ++d)
        acc += none[d] * w[((size_t)r*DIMN + d)*DIMN + e];
    out[r*DIMN + e] = acc;
}

// L[rb][t] = exp((dot(sc_none[r], tar_emb[b][t]) + (1-tmask)*-1e10)/16)
// grid (rb=64, tchunk=4), block 256: 128 t per block, 2 e-halves per t.
__global__ void initL_kernel(const float* __restrict__ sc_none,
                             const float* __restrict__ tar_emb,
                             const float* __restrict__ tar_mask,
                             float* __restrict__ L)
{
    __shared__ float sn[DIMN];
    __shared__ float part[256];
    int rb = blockIdx.x, r = rb >> 3, b = rb & 7;
    int tl = threadIdx.x & 127, half = threadIdx.x >> 7;
    int t = blockIdx.y * 128 + tl;
    sn[threadIdx.x] = sc_none[r*DIMN + threadIdx.x];
    __syncthreads();
    const float4* row = (const float4*)(tar_emb + ((size_t)b*TN + t)*DIMN + half*128);
    float acc = 0.f;
    #pragma unroll
    for (int k = 0; k < 32; ++k) {
        float4 v = row[k];
        int e = half*128 + k*4;
        acc += v.x*sn[e] + v.y*sn[e+1] + v.z*sn[e+2] + v.w*sn[e+3];
    }
    part[threadIdx.x] = acc;
    __syncthreads();
    if (half == 0) {
        float s = part[tl] + part[tl + 128];
        float tm = tar_mask[b*TN + t];
        L[(size_t)rb*TN + t] = __expf((s + (1.f - tm) * -1e10f) * 0.0625f);
    }
}

extern "C" void kernel_launch(void* const* d_in, const int* in_sizes, int n_in,
                              void* d_out, int out_size, void* d_ws, size_t ws_size,
                              hipStream_t stream)
{
    const float* src_emb  = (const float*)d_in[0];
    const float* tar_emb  = (const float*)d_in[1];
    const float* src_mask = (const float*)d_in[2];
    const float* tar_mask = (const float*)d_in[3];
    const float* w_score  = (const float*)d_in[4];
    const float* w_emb    = (const float*)d_in[5];
    const float* src_none = (const float*)d_in[6];
    // tar_none_node (d_in[7]) provably never reaches the output (t=512 sliced off)

    size_t off = 0;
    auto alloc = [&](size_t bytes) {
        char* q = (char*)d_ws + off;
        off += (bytes + 255) & ~(size_t)255;
        return q;
    };
    unsigned short* src_bf  = (unsigned short*)alloc((size_t)BN_*SN*DIMN*2);      // 2 MB
    unsigned short* tar_bf  = (unsigned short*)alloc((size_t)BN_*TN*DIMN*2);      // 2 MB
    unsigned short* wscT    = (unsigned short*)alloc((size_t)RELN*DIMN*DIMN*2);   // 1 MB
    unsigned short* wembT   = (unsigned short*)alloc((size_t)RELN*DIMN*DIMN*2);   // 1 MB
    unsigned short* scores  = (unsigned short*)alloc((size_t)RELN*BN_*SN*DIMN*2); // 16 MB
    unsigned short* wbuf    = (unsigned short*)alloc((size_t)RELN*BN_*SN*TN*2);   // 32 MB
    unsigned short* relT    = (unsigned short*)alloc((size_t)RELN*BN_*DIMN*TN*2); // 16 MB
    float*          sc_none = (float*)alloc((size_t)RELN*DIMN*4);
    float*          Lsum    = (float*)alloc((size_t)RELN*BN_*TN*4);               // 128 KB
    if (off > ws_size) return;  // fails loudly (output stays zero)

    hipMemsetAsync(d_out, 0, (size_t)out_size * 4, stream);

    cvt_bf16_kernel<<<1024, 256, 0, stream>>>(src_emb, src_bf, BN_*SN*DIMN);
    cvt_bf16_kernel<<<1024, 256, 0, stream>>>(tar_emb, tar_bf, BN_*TN*DIMN);
    wtrans_kernel<<<dim3(8,8,8), 256, 0, stream>>>(w_score, wscT);
    wtrans_kernel<<<dim3(8,8,8), 256, 0, stream>>>(w_emb,  wembT);
    scores_none_kernel<<<RELN, 256, 0, stream>>>(w_score, src_none, sc_none);
    // L[rb][t] seeded with the none-node row's exp (this is the only place
    // the source none-node affects the output)
    initL_kernel<<<dim3(64, 4), 256, 0, stream>>>(sc_none, tar_emb, tar_mask, Lsum);

    // GEMM1: scores (R, B*S, DIM) = src_bf (B*S, DIM) @ WscoreT[r]
    gemm_bt<1><<<dim3(32, 2, 8), 256, 0, stream>>>(src_bf, wscT, scores, DIMN, DIMN, DIMN,
                                                   nullptr, nullptr, nullptr);
    // GEMM2: w~ (R*B, S, T) bf16 = exp(mask(scores @ tar^T)/16), L += colsums
    gemm_bt<2><<<dim3(4, 4, 64), 256, 0, stream>>>(scores, tar_bf, wbuf, DIMN, DIMN, DIMN,
                                                   src_mask, tar_mask, Lsum);
    // GEMM3: relT (R,B,DIM,T) bf16 = (tar_bf @ WembT[r])/L, transposed store
    gemm_bt<3><<<dim3(32, 2, 8), 256, 0, stream>>>(tar_bf, wembT, relT, DIMN, DIMN, DIMN,
                                                   nullptr, nullptr, Lsum);
    // GEMM4: out (B*S, DIM) += w~[r,b] @ relT[r,b]^T * 1/sqrt(8), atomic over r
    gemm_bt<4><<<dim3(32, 2, 8), 256, 0, stream>>>(wbuf, relT, d_out, TN, TN, TN,
                                                   nullptr, nullptr, nullptr);
}